// Round 8
// baseline (610.412 us; speedup 1.0000x reference)
//
#include <hip/hip_runtime.h>

#define BATCH 16384
#define KDIM  3072
#define NDIM  3072

typedef __bf16 bf16;
typedef bf16  bf16x8  __attribute__((ext_vector_type(8)));
typedef float f32x4   __attribute__((ext_vector_type(4)));

// async global->LDS, 16B per lane. HW dest = wave-uniform base + lane*16.
__device__ __forceinline__ void g2l16(const bf16* g, bf16* l) {
    __builtin_amdgcn_global_load_lds(
        (__attribute__((address_space(1))) unsigned int*)g,
        (__attribute__((address_space(3))) unsigned int*)l,
        16, 0, 0);
}

// ---- prep 1: fp32 inputs -> bf16, 8 elems/thread ----
__global__ __launch_bounds__(256) void cvt_a_kernel(const float* __restrict__ in,
                                                    bf16* __restrict__ out) {
    const long idx = (long)blockIdx.x * 256 + threadIdx.x;
    const float4* in4 = (const float4*)in;
    float4 a = in4[idx * 2];
    float4 b = in4[idx * 2 + 1];
    bf16x8 o;
    o[0] = (bf16)a.x; o[1] = (bf16)a.y; o[2] = (bf16)a.z; o[3] = (bf16)a.w;
    o[4] = (bf16)b.x; o[5] = (bf16)b.y; o[6] = (bf16)b.z; o[7] = (bf16)b.w;
    ((bf16x8*)out)[idx] = o;
}

// ---- prep 2: Weff_t[u][i] = bf16(w[i][u] * mask[u][i]) via LDS transpose ----
__global__ __launch_bounds__(256) void weff_kernel(const float* __restrict__ w,
                                                   const int* __restrict__ mask,
                                                   bf16* __restrict__ wt) {
    __shared__ float tile[32][33];
    const int i0 = blockIdx.x * 32;
    const int u0 = blockIdx.y * 32;
    const int tx = threadIdx.x, ty = threadIdx.y;
#pragma unroll
    for (int r = 0; r < 4; r++)
        tile[ty + 8 * r][tx] = w[(long)(i0 + ty + 8 * r) * NDIM + u0 + tx];
    __syncthreads();
#pragma unroll
    for (int r = 0; r < 4; r++) {
        int u = u0 + ty + 8 * r;
        int i = i0 + tx;
        float v = tile[tx][ty + 8 * r] * (float)mask[(long)u * KDIM + i];
        wt[(long)u * KDIM + i] = (bf16)v;
    }
}

// ---- main GEMM (round-5: pipe OVERLAP within phase) ----
// Round-4 structure kept: 256x256 tile, BK=64, 8 waves, straddled quadrants,
// quadrant-major phases, staircase staging, vmcnt(4) once per tile, swizzle.
// Round-4 counters showed LDS pipe (2000 cyc/tile) and MFMA pipe (2065
// cyc/tile) running SERIALLY: the per-phase lgkmcnt(0)+sched_barrier drain
// kept the matrix pipe idle during the read burst. Round-5 change:
//  - drop the forced lgkmcnt(0) drain + opening barrier per phase;
//  - ds_reads feed MFMAs via data deps -> compiler emits COUNTED lgkmcnt,
//    so reads complete under the MFMA cluster (within-phase overlap);
//  - one sched_barrier(0) at phase END pins MFMAs above the closing barrier
//    (rule-18: register-only MFMAs otherwise sink past asm barriers);
//  - 1 barrier/phase (4/tile). Staircase hazard ledger: every LDS slot has
//    >=2 phases (>=2 barriers) between last-read and overwrite; reads retire
//    before their wave's closing barrier (consumer-forced waits). Tile
//    arrival still guarded by vmcnt(4)+barrier at p4.
__global__ __launch_bounds__(512, 2) void gemm_kernel(const bf16* __restrict__ A,   // [BATCH][KDIM]
                                                      const bf16* __restrict__ Bt,  // [NDIM][KDIM]
                                                      const float* __restrict__ bias,
                                                      float* __restrict__ C) {      // [BATCH][NDIM]
    __shared__ __align__(16) bf16 lds[2 * 32768];  // 128 KiB

    const int tid  = threadIdx.x;
    const int lane = tid & 63;
    const int wv   = tid >> 6;
    const int l15  = lane & 15;
    const int l4   = lane >> 4;        // 0..3
    const int sx   = l15 & 7;
    const int wm   = (wv >> 2) * 64;   // 0 or 64
    const int wn   = (wv & 3) * 32;    // 0,32,64,96

    // T1: XCD swizzle, 768 blocks % 8 == 0 -> bijective.
    const int lid = blockIdx.y * gridDim.x + blockIdx.x;  // grid = (12, 64)
    const int sid = (lid & 7) * 96 + (lid >> 3);
    const long m0 = (long)(sid / 12) * 256;
    const long n0 = (long)(sid % 12) * 256;

    // staging: thread t -> row t>>3 (+64 for 2nd call), chunk t&7, source
    // chunk pre-swizzled (t&7)^((t>>3)&7); dest linear tid*16B per call.
    const int srow = tid >> 3;
    const int gsc  = (tid & 7) ^ (srow & 7);
    const bf16* gAb = A  + (m0 + srow) * (long)KDIM + gsc * 8;
    const bf16* gBb = Bt + (n0 + srow) * (long)KDIM + gsc * 8;

#define STAGE_A(Q, KT, H) do {                                                  \
    const bf16* g_ = gAb + (long)((H) * 128) * KDIM + (long)(KT) * 64;          \
    bf16* d_ = &lds[(Q) * 32768 + (H) * 8192 + tid * 8];                        \
    g2l16(g_, d_);                                                              \
    g2l16(g_ + (long)64 * KDIM, d_ + 4096);                                     \
} while (0)
#define STAGE_B(Q, KT, H) do {                                                  \
    const bf16* g_ = gBb + (long)((H) * 128) * KDIM + (long)(KT) * 64;          \
    bf16* d_ = &lds[(Q) * 32768 + 16384 + (H) * 8192 + tid * 8];                \
    g2l16(g_, d_);                                                              \
    g2l16(g_ + (long)64 * KDIM, d_ + 4096);                                     \
} while (0)

    // fragment addressing (elem units; 64-elem = 128B rows, 8 chunks)
    const int aRow = (wm + l15) * 64;
    const int bRow = (wn + l15) * 64;
    const int cc0  = (l4 ^ sx) * 8;   // ks=0 chunk offset (swizzled)
    const int cc1  = cc0 ^ 32;        // ks=1: chunk^4 -> elems^32

    bf16x8 aF[4][2];   // current m-half A frags
    bf16x8 bF[4][2];   // all-tile-resident B frags (fn 0..3)
    f32x4  acc[8][4] = {};

#define RDA(BP, MH)                                                             \
    _Pragma("unroll") for (int f_ = 0; f_ < 4; ++f_) {                          \
        aF[f_][0] = *(const bf16x8*)((BP) + (MH) * 8192 + aRow + f_ * 1024 + cc0); \
        aF[f_][1] = *(const bf16x8*)((BP) + (MH) * 8192 + aRow + f_ * 1024 + cc1); \
    }
#define RDB(BP, NH)                                                             \
    _Pragma("unroll") for (int n_ = 0; n_ < 2; ++n_) {                          \
        bF[(NH) * 2 + n_][0] = *(const bf16x8*)((BP) + 16384 + (NH) * 8192 + bRow + n_ * 1024 + cc0); \
        bF[(NH) * 2 + n_][1] = *(const bf16x8*)((BP) + 16384 + (NH) * 8192 + bRow + n_ * 1024 + cc1); \
    }
#define MMQ(MH, NH)                                                             \
    _Pragma("unroll") for (int ks_ = 0; ks_ < 2; ++ks_)                         \
    _Pragma("unroll") for (int f_ = 0; f_ < 4; ++f_)                            \
    _Pragma("unroll") for (int n_ = 0; n_ < 2; ++n_)                            \
        acc[(MH) * 4 + f_][(NH) * 2 + n_] = __builtin_amdgcn_mfma_f32_16x16x32_bf16( \
            aF[f_][ks_], bF[(NH) * 2 + n_][ks_], acc[(MH) * 4 + f_][(NH) * 2 + n_], 0, 0, 0)

// Phase: reads + stage + MFMAs free to interleave (counted lgkmcnt from data
// deps); sched_barrier(0) pins everything above the closing barrier; fences
// stop memory-op motion across the barrier.
#define PHASE(P, MH, NH, READS, STAGE_STMT, DOVM) do {                          \
    const bf16* bp_ = &lds[(P) * 32768];                                        \
    READS;                                                                      \
    STAGE_STMT;                                                                 \
    __builtin_amdgcn_s_setprio(1);                                              \
    MMQ(MH, NH);                                                                \
    __builtin_amdgcn_s_setprio(0);                                              \
    __builtin_amdgcn_sched_barrier(0);                                          \
    if (DOVM) asm volatile("s_waitcnt vmcnt(4)" ::: "memory");                  \
    asm volatile("" ::: "memory");                                              \
    __builtin_amdgcn_s_barrier();                                               \
    asm volatile("" ::: "memory");                                              \
} while (0)

#define RD_AB(MH, NH) RDB(bp_, NH); RDA(bp_, MH)
#define RD_ONLYB(NH)  RDB(bp_, NH)
#define RD_ONLYA(MH)  RDA(bp_, MH)
#define RD_NONE       ((void)0)

    // prologue: T0 all 4 halves + A0(T1),B0(T1); wait leaves T1's 4 loads.
    STAGE_A(0, 0, 0);  // A0(T0)
    STAGE_B(0, 0, 0);  // B0(T0)
    STAGE_B(0, 0, 1);  // B1(T0)
    STAGE_A(0, 0, 1);  // A1(T0)
    STAGE_A(1, 1, 0);  // A0(T1)
    STAGE_B(1, 1, 0);  // B0(T1)
    asm volatile("s_waitcnt vmcnt(4)" ::: "memory");
    __builtin_amdgcn_s_barrier();
    asm volatile("" ::: "memory");

    const int NT = KDIM / 64;  // 48 (even)
#pragma unroll 1
    for (int t = 0; t < NT; t += 2) {
        const int k1 = t + 1;                       // <= 47
        const int k2 = (t + 2 < NT) ? t + 2 : 0;    // wrap: dummy re-stage
        const int k3 = (t + 3 < NT) ? t + 3 : t + 3 - NT;
        // tile t (buf 0)
        PHASE(0, 0, 0, RD_AB(0, 0),  STAGE_B(1, k1, 1), 0);  // p1
        PHASE(0, 0, 1, RD_ONLYB(1),  STAGE_A(1, k1, 1), 0);  // p2
        PHASE(0, 1, 0, RD_ONLYA(1),  STAGE_A(0, k2, 0), 0);  // p3
        PHASE(0, 1, 1, RD_NONE,      STAGE_B(0, k2, 0), 1);  // p4 + vmcnt(4)
        // tile t+1 (buf 1)
        PHASE(1, 0, 0, RD_AB(0, 0),  STAGE_B(0, k2, 1), 0);  // p1
        PHASE(1, 0, 1, RD_ONLYB(1),  STAGE_A(0, k2, 1), 0);  // p2
        PHASE(1, 1, 0, RD_ONLYA(1),  STAGE_A(1, k3, 0), 0);  // p3
        PHASE(1, 1, 1, RD_NONE,      STAGE_B(1, k3, 0), 1);  // p4 + vmcnt(4)
    }
    asm volatile("s_waitcnt vmcnt(0)" ::: "memory");  // drain dummy stages

    // epilogue: 16x16x32 C/D layout col=lane&15, row=(lane>>4)*4+reg
    float bv[4];
#pragma unroll
    for (int n_ = 0; n_ < 4; ++n_) {
        const long gc = n0 + ((n_ < 2) ? (wn + n_ * 16) : (128 + wn + (n_ - 2) * 16)) + l15;
        bv[n_] = bias[gc];
    }
#pragma unroll
    for (int f_ = 0; f_ < 8; ++f_) {
        const long gm = m0 + ((f_ < 4) ? (wm + f_ * 16) : (128 + wm + (f_ - 4) * 16)) + l4 * 4;
#pragma unroll
        for (int n_ = 0; n_ < 4; ++n_) {
            const long gc = n0 + ((n_ < 2) ? (wn + n_ * 16) : (128 + wn + (n_ - 2) * 16)) + l15;
#pragma unroll
            for (int r_ = 0; r_ < 4; ++r_)
                C[(gm + r_) * NDIM + gc] = acc[f_][n_][r_] + bv[n_];
        }
    }
#undef STAGE_A
#undef STAGE_B
#undef RDA
#undef RDB
#undef MMQ
#undef PHASE
#undef RD_AB
#undef RD_ONLYB
#undef RD_ONLYA
#undef RD_NONE
}

// ---- fallback (only if ws_size too small): naive fp32 masked GEMM ----
__global__ __launch_bounds__(256) void naive_kernel(const float* __restrict__ x,
                                                    const float* __restrict__ w,
                                                    const float* __restrict__ bias,
                                                    const int* __restrict__ mask,
                                                    float* __restrict__ out) {
    const long idx = (long)blockIdx.x * 256 + threadIdx.x;
    const long bi = idx / NDIM;
    const int u = (int)(idx % NDIM);
    float s = 0.f;
    for (int k = 0; k < KDIM; k++)
        s += x[bi * KDIM + k] * w[(long)k * NDIM + u] * (float)mask[(long)u * KDIM + k];
    out[idx] = s + bias[u];
}

extern "C" void kernel_launch(void* const* d_in, const int* in_sizes, int n_in,
                              void* d_out, int out_size, void* d_ws, size_t ws_size,
                              hipStream_t stream) {
    const float* x    = (const float*)d_in[0];  // [16384, 3072] fp32
    const float* w    = (const float*)d_in[1];  // [3072, 3072] fp32
    const float* bias = (const float*)d_in[2];  // [3072] fp32
    const int*   mask = (const int*)d_in[3];    // [3072, 3072] int32
    float* out = (float*)d_out;                 // [16384, 3072] fp32

    const size_t needA = (size_t)BATCH * KDIM * sizeof(bf16);  // ~100.7 MB
    const size_t needW = (size_t)NDIM * KDIM * sizeof(bf16);   // ~18.9 MB

    if (ws_size < needA + needW) {
        const long total = (long)BATCH * NDIM;
        naive_kernel<<<(int)(total / 256), 256, 0, stream>>>(x, w, bias, mask, out);
        return;
    }

    bf16* Abf = (bf16*)d_ws;
    bf16* Wt  = (bf16*)((char*)d_ws + needA);

    cvt_a_kernel<<<(BATCH * (KDIM / 8)) / 256, 256, 0, stream>>>(x, Abf);
    weff_kernel<<<dim3(KDIM / 32, NDIM / 32), dim3(32, 8), 0, stream>>>(w, mask, Wt);
    gemm_kernel<<<dim3(NDIM / 256, BATCH / 256), 512, 0, stream>>>(Abf, Wt, bias, out);
}

// Round 10
// 608.856 us; speedup vs baseline: 1.0026x; 1.0026x over previous
//
#include <hip/hip_runtime.h>

#define BATCH 16384
#define KDIM  3072
#define NDIM  3072

typedef __bf16 bf16;
typedef bf16  bf16x8  __attribute__((ext_vector_type(8)));
typedef float f32x4   __attribute__((ext_vector_type(4)));

// async global->LDS, 16B per lane. HW dest = wave-uniform base + lane*16.
__device__ __forceinline__ void g2l16(const bf16* g, bf16* l) {
    __builtin_amdgcn_global_load_lds(
        (__attribute__((address_space(1))) unsigned int*)g,
        (__attribute__((address_space(3))) unsigned int*)l,
        16, 0, 0);
}

// ---- prep 1: fp32 inputs -> bf16, 8 elems/thread ----
__global__ __launch_bounds__(256) void cvt_a_kernel(const float* __restrict__ in,
                                                    bf16* __restrict__ out) {
    const long idx = (long)blockIdx.x * 256 + threadIdx.x;
    const float4* in4 = (const float4*)in;
    float4 a = in4[idx * 2];
    float4 b = in4[idx * 2 + 1];
    bf16x8 o;
    o[0] = (bf16)a.x; o[1] = (bf16)a.y; o[2] = (bf16)a.z; o[3] = (bf16)a.w;
    o[4] = (bf16)b.x; o[5] = (bf16)b.y; o[6] = (bf16)b.z; o[7] = (bf16)b.w;
    ((bf16x8*)out)[idx] = o;
}

// ---- prep 2: Weff_t[u][i] = bf16(w[i][u] * mask[u][i]) via LDS transpose ----
__global__ __launch_bounds__(256) void weff_kernel(const float* __restrict__ w,
                                                   const int* __restrict__ mask,
                                                   bf16* __restrict__ wt) {
    __shared__ float tile[32][33];
    const int i0 = blockIdx.x * 32;
    const int u0 = blockIdx.y * 32;
    const int tx = threadIdx.x, ty = threadIdx.y;
#pragma unroll
    for (int r = 0; r < 4; r++)
        tile[ty + 8 * r][tx] = w[(long)(i0 + ty + 8 * r) * NDIM + u0 + tx];
    __syncthreads();
#pragma unroll
    for (int r = 0; r < 4; r++) {
        int u = u0 + ty + 8 * r;
        int i = i0 + tx;
        float v = tile[tx][ty + 8 * r] * (float)mask[(long)u * KDIM + i];
        wt[(long)u * KDIM + i] = (bf16)v;
    }
}

// ---- main GEMM (round-9: CROSS-PHASE fragment prefetch) ----
// Round-8 measured: LDS pipe (~2048 cyc/tile) and MFMA pipe (~2483 cyc/tile,
// per-CU rate) still ~serial (wall 4211 ~ sum): every phase had a same-phase
// reads->MFMA dependency, so barrier-aligned waves alternate LDS-burst /
// MFMA-burst. Round-9: ALL ds_reads prefetch the NEXT consuming phase,
// using the existing banks (A 32 + B0 16 + B1 16 VGPR, zero new regs):
//  p1: MFMA(0,0)[A0,B0 prefetched] ; read B1(T) ; stage A1(T+1)
//  p2: MFMA(0,1)[A0,B1] ; read A1(T) (after MFMAs, A-bank WAR by dep)
//      ; stage B1(T+1)
//  p3: MFMA(1,0)[A1,B0] ; stage A0(T+2)+B0(T+2) ; vmcnt(4) ; barrier
//  p4: MFMA(1,1)[A1,B1] ; read A0(T+1)+B0(T+1) from other buf (safe after
//      p3e vmcnt+barrier)
// vmcnt ledger: at each p3e, queue = 12 loads [A0B0(T+1)@p3(T-1), A1(T+1)@p1,
// B1(T+1)@p2, A0B0(T+2)@p3]; vmcnt(4) retires exactly tile T+1, 4 in flight.
// Slot hazards: every stage target has >=2 barriers since its last reads.
__global__ __launch_bounds__(512, 2) void gemm_kernel(const bf16* __restrict__ A,   // [BATCH][KDIM]
                                                      const bf16* __restrict__ Bt,  // [NDIM][KDIM]
                                                      const float* __restrict__ bias,
                                                      float* __restrict__ C) {      // [BATCH][NDIM]
    __shared__ __align__(16) bf16 lds[2 * 32768];  // 128 KiB

    const int tid  = threadIdx.x;
    const int lane = tid & 63;
    const int wv   = tid >> 6;
    const int l15  = lane & 15;
    const int l4   = lane >> 4;        // 0..3
    const int sx   = l15 & 7;
    const int wm   = (wv >> 2) * 64;   // 0 or 64
    const int wn   = (wv & 3) * 32;    // 0,32,64,96

    // T1: XCD swizzle, 768 blocks % 8 == 0 -> bijective.
    const int lid = blockIdx.y * gridDim.x + blockIdx.x;  // grid = (12, 64)
    const int sid = (lid & 7) * 96 + (lid >> 3);
    const long m0 = (long)(sid / 12) * 256;
    const long n0 = (long)(sid % 12) * 256;

    // staging: thread t -> row t>>3 (+64 for 2nd call), chunk t&7, source
    // chunk pre-swizzled (t&7)^((t>>3)&7); dest linear tid*16B per call.
    const int srow = tid >> 3;
    const int gsc  = (tid & 7) ^ (srow & 7);
    const bf16* gAb = A  + (m0 + srow) * (long)KDIM + gsc * 8;
    const bf16* gBb = Bt + (n0 + srow) * (long)KDIM + gsc * 8;

#define STAGE_A(Q, KT, H) do {                                                  \
    const bf16* g_ = gAb + (long)((H) * 128) * KDIM + (long)(KT) * 64;          \
    bf16* d_ = &lds[(Q) * 32768 + (H) * 8192 + tid * 8];                        \
    g2l16(g_, d_);                                                              \
    g2l16(g_ + (long)64 * KDIM, d_ + 4096);                                     \
} while (0)
#define STAGE_B(Q, KT, H) do {                                                  \
    const bf16* g_ = gBb + (long)((H) * 128) * KDIM + (long)(KT) * 64;          \
    bf16* d_ = &lds[(Q) * 32768 + 16384 + (H) * 8192 + tid * 8];                \
    g2l16(g_, d_);                                                              \
    g2l16(g_ + (long)64 * KDIM, d_ + 4096);                                     \
} while (0)

    // fragment addressing (elem units; 64-elem = 128B rows, 8 chunks)
    const int aRow = (wm + l15) * 64;
    const int bRow = (wn + l15) * 64;
    const int cc0  = (l4 ^ sx) * 8;   // ks=0 chunk offset (swizzled)
    const int cc1  = cc0 ^ 32;        // ks=1: chunk^4 -> elems^32

    bf16x8 aF[4][2];   // A bank: holds A0 during p1-p2, A1 during p3-p4
    bf16x8 bF[4][2];   // bF[0..1] = B0 bank, bF[2..3] = B1 bank
    f32x4  acc[8][4] = {};

#define RDA(BP, MH)                                                             \
    _Pragma("unroll") for (int f_ = 0; f_ < 4; ++f_) {                          \
        aF[f_][0] = *(const bf16x8*)((BP) + (MH) * 8192 + aRow + f_ * 1024 + cc0); \
        aF[f_][1] = *(const bf16x8*)((BP) + (MH) * 8192 + aRow + f_ * 1024 + cc1); \
    }
#define RDB(BP, NH)                                                             \
    _Pragma("unroll") for (int n_ = 0; n_ < 2; ++n_) {                          \
        bF[(NH) * 2 + n_][0] = *(const bf16x8*)((BP) + 16384 + (NH) * 8192 + bRow + n_ * 1024 + cc0); \
        bF[(NH) * 2 + n_][1] = *(const bf16x8*)((BP) + 16384 + (NH) * 8192 + bRow + n_ * 1024 + cc1); \
    }
#define MMQ(MH, NH)                                                             \
    _Pragma("unroll") for (int ks_ = 0; ks_ < 2; ++ks_)                         \
    _Pragma("unroll") for (int f_ = 0; f_ < 4; ++f_)                            \
    _Pragma("unroll") for (int n_ = 0; n_ < 2; ++n_)                            \
        acc[(MH) * 4 + f_][(NH) * 2 + n_] = __builtin_amdgcn_mfma_f32_16x16x32_bf16( \
            aF[f_][ks_], bF[(NH) * 2 + n_][ks_], acc[(MH) * 4 + f_][(NH) * 2 + n_], 0, 0, 0)

#define PRIO1 __builtin_amdgcn_s_setprio(1)
#define PRIO0 __builtin_amdgcn_s_setprio(0)
#define SB    __builtin_amdgcn_sched_barrier(0)
#define BAR   do { asm volatile("" ::: "memory"); __builtin_amdgcn_s_barrier(); \
                   asm volatile("" ::: "memory"); } while (0)
#define VM4   asm volatile("s_waitcnt vmcnt(4)" ::: "memory")

// One K-tile: P = buffer parity; K1 = t+1 index, K2 = t+2 index (wrapped).
#define TILE_BODY(P, K1, K2) do {                                               \
    const bf16* bp_ = &lds[(P) * 32768];                                        \
    const bf16* bq_ = &lds[((P) ^ 1) * 32768];                                  \
    /* p1: MFMA(0,0); prefetch B1(T); stage A1(T+1) */                          \
    RDB(bp_, 1);                                                                \
    STAGE_A((P) ^ 1, K1, 1);                                                    \
    PRIO1; MMQ(0, 0); PRIO0;                                                    \
    SB; BAR;                                                                    \
    /* p2: MFMA(0,1); stage B1(T+1); then read A1(T) (A-bank WAR -> after) */   \
    STAGE_B((P) ^ 1, K1, 1);                                                    \
    PRIO1; MMQ(0, 1); PRIO0;                                                    \
    RDA(bp_, 1);                                                                \
    SB; BAR;                                                                    \
    /* p3: MFMA(1,0); stage A0(T+2)+B0(T+2); vmcnt(4); barrier */               \
    STAGE_A(P, K2, 0);                                                          \
    STAGE_B(P, K2, 0);                                                          \
    PRIO1; MMQ(1, 0); PRIO0;                                                    \
    SB; VM4; BAR;                                                               \
    /* p4: MFMA(1,1); then prefetch A0(T+1)+B0(T+1) from other buffer */        \
    PRIO1; MMQ(1, 1); PRIO0;                                                    \
    RDA(bq_, 0);                                                                \
    RDB(bq_, 0);                                                                \
    SB; BAR;                                                                    \
} while (0)

    // prologue: stage T0 fully + T1's A0,B0; wait T0; prefetch A0,B0(T0).
    STAGE_A(0, 0, 0);  // A0(T0)
    STAGE_B(0, 0, 0);  // B0(T0)
    STAGE_A(0, 0, 1);  // A1(T0)
    STAGE_B(0, 0, 1);  // B1(T0)
    STAGE_A(1, 1, 0);  // A0(T1)
    STAGE_B(1, 1, 0);  // B0(T1)
    asm volatile("s_waitcnt vmcnt(4)" ::: "memory");
    __builtin_amdgcn_s_barrier();
    asm volatile("" ::: "memory");
    RDA(&lds[0], 0);   // A0(T0) -> A bank
    RDB(&lds[0], 0);   // B0(T0) -> B0 bank

    const int NT = KDIM / 64;  // 48 (even)
#pragma unroll 1
    for (int t = 0; t < NT; t += 2) {
        const int k1a = t + 1;                      // <= 47
        const int k2a = (t + 2 < NT) ? t + 2 : 0;   // wrap: dummy re-stage
        const int k1b = (t + 2 < NT) ? t + 2 : 0;
        const int k2b = (t + 3 < NT) ? t + 3 : 0;
        TILE_BODY(0, k1a, k2a);   // tile t   (buf 0)
        TILE_BODY(1, k1b, k2b);   // tile t+1 (buf 1)
    }
    asm volatile("s_waitcnt vmcnt(0)" ::: "memory");  // drain dummy stages

    // epilogue: 16x16x32 C/D layout col=lane&15, row=(lane>>4)*4+reg
    float bv[4];
#pragma unroll
    for (int n_ = 0; n_ < 4; ++n_) {
        const long gc = n0 + ((n_ < 2) ? (wn + n_ * 16) : (128 + wn + (n_ - 2) * 16)) + l15;
        bv[n_] = bias[gc];
    }
#pragma unroll
    for (int f_ = 0; f_ < 8; ++f_) {
        const long gm = m0 + ((f_ < 4) ? (wm + f_ * 16) : (128 + wm + (f_ - 4) * 16)) + l4 * 4;
#pragma unroll
        for (int n_ = 0; n_ < 4; ++n_) {
            const long gc = n0 + ((n_ < 2) ? (wn + n_ * 16) : (128 + wn + (n_ - 2) * 16)) + l15;
#pragma unroll
            for (int r_ = 0; r_ < 4; ++r_)
                C[(gm + r_) * NDIM + gc] = acc[f_][n_][r_] + bv[n_];
        }
    }
#undef STAGE_A
#undef STAGE_B
#undef RDA
#undef RDB
#undef MMQ
#undef TILE_BODY
#undef PRIO1
#undef PRIO0
#undef SB
#undef BAR
#undef VM4
}

// ---- fallback (only if ws_size too small): naive fp32 masked GEMM ----
__global__ __launch_bounds__(256) void naive_kernel(const float* __restrict__ x,
                                                    const float* __restrict__ w,
                                                    const float* __restrict__ bias,
                                                    const int* __restrict__ mask,
                                                    float* __restrict__ out) {
    const long idx = (long)blockIdx.x * 256 + threadIdx.x;
    const long bi = idx / NDIM;
    const int u = (int)(idx % NDIM);
    float s = 0.f;
    for (int k = 0; k < KDIM; k++)
        s += x[bi * KDIM + k] * w[(long)k * NDIM + u] * (float)mask[(long)u * KDIM + k];
    out[idx] = s + bias[u];
}

extern "C" void kernel_launch(void* const* d_in, const int* in_sizes, int n_in,
                              void* d_out, int out_size, void* d_ws, size_t ws_size,
                              hipStream_t stream) {
    const float* x    = (const float*)d_in[0];  // [16384, 3072] fp32
    const float* w    = (const float*)d_in[1];  // [3072, 3072] fp32
    const float* bias = (const float*)d_in[2];  // [3072] fp32
    const int*   mask = (const int*)d_in[3];    // [3072, 3072] int32
    float* out = (float*)d_out;                 // [16384, 3072] fp32

    const size_t needA = (size_t)BATCH * KDIM * sizeof(bf16);  // ~100.7 MB
    const size_t needW = (size_t)NDIM * KDIM * sizeof(bf16);   // ~18.9 MB

    if (ws_size < needA + needW) {
        const long total = (long)BATCH * NDIM;
        naive_kernel<<<(int)(total / 256), 256, 0, stream>>>(x, w, bias, mask, out);
        return;
    }

    bf16* Abf = (bf16*)d_ws;
    bf16* Wt  = (bf16*)((char*)d_ws + needA);

    cvt_a_kernel<<<(BATCH * (KDIM / 8)) / 256, 256, 0, stream>>>(x, Abf);
    weff_kernel<<<dim3(KDIM / 32, NDIM / 32), dim3(32, 8), 0, stream>>>(w, mask, Wt);
    gemm_kernel<<<dim3(NDIM / 256, BATCH / 256), 512, 0, stream>>>(Abf, Wt, bias, out);
}